// Round 6
// baseline (158.394 us; speedup 1.0000x reference)
//
#include <hip/hip_runtime.h>

#define F      128
#define RSH    5            // 32 nodes per bucket
#define RNODES 32
#define NBUCK  1563         // ceil(50000/32) — N fixed at 50000
#define CB     1280         // bucket capacity (mean 1024, +8 sigma)
#define CH     8192         // edges per partition chunk
#define OVCAP  65536

typedef __attribute__((ext_vector_type(8))) short short8;   // 8 bf16
typedef __attribute__((ext_vector_type(4))) float f32x4;    // MFMA C/D frag

__device__ inline short f2bf(float f) {        // fp32 -> bf16 RNE
  unsigned u = __float_as_uint(f);
  u += 0x7fff + ((u >> 16) & 1);
  return (short)(u >> 16);
}
__device__ inline float bf2f(unsigned short u) {
  return __uint_as_float((unsigned)u << 16);
}

// ---------------------------------------------------------------------------
// Init: bucket cursors at region base; overflow count = 0.
// ---------------------------------------------------------------------------
__global__ __launch_bounds__(256) void k_init(unsigned* gcur, unsigned* ovcnt) {
  const int i = blockIdx.x * blockDim.x + threadIdx.x;
  if (i < NBUCK) gcur[i] = (unsigned)i * CB;
  else if (i == NBUCK) *ovcnt = 0;
}

// ---------------------------------------------------------------------------
// Pack W into MFMA B-fragments (bf16), one-time 32KB buffer (L1/L2-resident).
// ---------------------------------------------------------------------------
__global__ __launch_bounds__(256) void k_packW(
    const float* __restrict__ W, short* __restrict__ Wp) {
  for (int fid = threadIdx.x; fid < 2048; fid += 256) {
    const int lane = fid & 63;
    const int c    = (fid >> 6) & 3;
    const int jt   = fid >> 8;
    const int j    = jt * 16 + (lane & 15);
    const int k0   = c * 32 + (lane >> 4) * 8;
    short8 s;
    #pragma unroll
    for (int i = 0; i < 8; ++i) s[i] = f2bf(W[j * F + k0 + i]);
    *reinterpret_cast<short8*>(Wp + fid * 8) = s;
  }
}

// ---------------------------------------------------------------------------
// Y = X @ W^T via mfma_f32_16x16x32_bf16; output bf16 in COLUMN-SLICED layout
// Ys[s][row][c]  (s = col>>5, c = col&31): each 32-col slice is 3.2 MB ->
// per-XCD-L2-resident during the sliced reduce.
// Verified mapping: col=jt*16+(lane&15); row=row0+(lane>>4)*4+reg.
// ---------------------------------------------------------------------------
__global__ __launch_bounds__(256) void k_gemm(
    const float* __restrict__ X, const short* __restrict__ Wp,
    unsigned short* __restrict__ Ys, int N, int nTiles) {
  const int lane = threadIdx.x & 63;
  const int tile = blockIdx.x * 4 + (threadIdx.x >> 6);
  if (tile >= nTiles) return;
  const int row0 = tile * 16;
  const int r    = row0 + (lane & 15);
  const int k0   = (lane >> 4) * 8;
  const size_t NS = (size_t)N * 32;

  short8 a[4];
  #pragma unroll
  for (int c = 0; c < 4; ++c) {
    if (r < N) {
      const float* p = X + (size_t)r * F + c * 32 + k0;
      const float4 x0 = *reinterpret_cast<const float4*>(p);
      const float4 x1 = *reinterpret_cast<const float4*>(p + 4);
      a[c][0] = f2bf(x0.x); a[c][1] = f2bf(x0.y);
      a[c][2] = f2bf(x0.z); a[c][3] = f2bf(x0.w);
      a[c][4] = f2bf(x1.x); a[c][5] = f2bf(x1.y);
      a[c][6] = f2bf(x1.z); a[c][7] = f2bf(x1.w);
    } else {
      #pragma unroll
      for (int i = 0; i < 8; ++i) a[c][i] = 0;
    }
  }

  #pragma unroll
  for (int jt = 0; jt < 8; ++jt) {
    f32x4 acc = {0.f, 0.f, 0.f, 0.f};
    #pragma unroll
    for (int c = 0; c < 4; ++c) {
      const short8 bfrag = *reinterpret_cast<const short8*>(
          Wp + ((jt * 4 + c) * 64 + lane) * 8);
      acc = __builtin_amdgcn_mfma_f32_16x16x32_bf16(a[c], bfrag, acc, 0, 0, 0);
    }
    const int col   = jt * 16 + (lane & 15);
    const int rbase = row0 + (lane >> 4) * 4;
    unsigned short* dst = Ys + (size_t)(col >> 5) * NS + (col & 31);
    #pragma unroll
    for (int reg = 0; reg < 4; ++reg)
      if (rbase + reg < N)
        dst[(size_t)(rbase + reg) * 32] = (unsigned short)f2bf(acc[reg]);
  }
}

// ---------------------------------------------------------------------------
// Multisplit partition (verbatim from R4 — proven).
// Entry = src(16b) | dst_local(5b)<<16 | bucket(11b)<<21.
// ---------------------------------------------------------------------------
__global__ __launch_bounds__(512) void k_partition(
    const int* __restrict__ src, const int* __restrict__ dst,
    unsigned* __restrict__ pk, unsigned* __restrict__ gcur,
    unsigned* __restrict__ ovcnt, unsigned long long* __restrict__ ovlist,
    int E) {
  __shared__ unsigned lpk[CH];
  __shared__ unsigned cnt[NBUCK];
  __shared__ unsigned offs[NBUCK];
  __shared__ unsigned cur[NBUCK];
  __shared__ unsigned gbase[NBUCK];
  const int t = threadIdx.x;
  const int nchunk = (E + CH - 1) / CH;

  for (int c = blockIdx.x; c < nchunk; c += gridDim.x) {
    const int e0   = c * CH;
    const int ecnt = min(CH, E - e0);

    for (int i = t; i < NBUCK; i += 512) cnt[i] = 0;
    __syncthreads();

    for (int i = t; i < ecnt; i += 512)
      atomicAdd(&cnt[(unsigned)dst[e0 + i] >> RSH], 1u);
    __syncthreads();

    unsigned lv0, lv1, lv2, lv3;
    {
      const int i0 = t * 4;
      lv0 = (i0 + 0 < NBUCK) ? cnt[i0 + 0] : 0;
      lv1 = (i0 + 1 < NBUCK) ? cnt[i0 + 1] : 0;
      lv2 = (i0 + 2 < NBUCK) ? cnt[i0 + 2] : 0;
      lv3 = (i0 + 3 < NBUCK) ? cnt[i0 + 3] : 0;
    }
    cur[t] = lv0 + lv1 + lv2 + lv3;
    __syncthreads();
    for (int d2 = 1; d2 < 512; d2 <<= 1) {
      const unsigned add = (t >= d2) ? cur[t - d2] : 0;
      __syncthreads();
      cur[t] += add;
      __syncthreads();
    }
    unsigned ebase = (t > 0) ? cur[t - 1] : 0;
    __syncthreads();
    {
      const int i0 = t * 4;
      if (i0 + 0 < NBUCK) { offs[i0 + 0] = ebase; cur[i0 + 0] = ebase; ebase += lv0; }
      if (i0 + 1 < NBUCK) { offs[i0 + 1] = ebase; cur[i0 + 1] = ebase; ebase += lv1; }
      if (i0 + 2 < NBUCK) { offs[i0 + 2] = ebase; cur[i0 + 2] = ebase; ebase += lv2; }
      if (i0 + 3 < NBUCK) { offs[i0 + 3] = ebase; cur[i0 + 3] = ebase; ebase += lv3; }
    }
    __syncthreads();

    for (int i = t; i < ecnt; i += 512) {
      const unsigned d = (unsigned)dst[e0 + i];
      const unsigned b = d >> RSH;
      const unsigned p = atomicAdd(&cur[b], 1u);
      lpk[p] = (unsigned)src[e0 + i] | ((d & (RNODES - 1)) << 16) | (b << 21);
    }
    __syncthreads();

    for (int i = t; i < NBUCK; i += 512)
      if (cnt[i] > 0) gbase[i] = atomicAdd(&gcur[i], cnt[i]);
    __syncthreads();

    for (int p = t; p < ecnt; p += 512) {
      const unsigned v = lpk[p];
      const unsigned b = v >> 21;
      const unsigned idx = gbase[b] + ((unsigned)p - offs[b]);
      if (idx < (b + 1) * (unsigned)CB) {
        pk[idx] = v & 0x1FFFFFu;
      } else {
        const unsigned o = atomicAdd(ovcnt, 1u);
        if (o < OVCAP) {
          const unsigned s  = v & 0xFFFFu;
          const unsigned dl = (v >> 16) & (RNODES - 1);
          ovlist[o] = ((unsigned long long)(b * RNODES + dl) << 32) | s;
        }
      }
    }
    __syncthreads();
  }
}

// ---------------------------------------------------------------------------
// Per-bucket CSR (verbatim from R4 — proven).
// ---------------------------------------------------------------------------
__global__ __launch_bounds__(256) void k_csr(
    const unsigned* __restrict__ pk, const unsigned* __restrict__ gcur,
    unsigned short* __restrict__ csr, int* __restrict__ offsets,
    int* __restrict__ counts, int N) {
  __shared__ unsigned lcnt[RNODES], loffs[RNODES], lcur[RNODES];
  const int b = blockIdx.x;
  const unsigned base = (unsigned)b * CB;
  const unsigned m = min(gcur[b] - base, (unsigned)CB);
  const int t = threadIdx.x;
  if (t < RNODES) lcnt[t] = 0;
  __syncthreads();
  for (unsigned i = t; i < m; i += 256)
    atomicAdd(&lcnt[pk[base + i] >> 16], 1u);
  __syncthreads();
  if (t == 0) {
    unsigned r = 0;
    #pragma unroll
    for (int i = 0; i < RNODES; ++i) { loffs[i] = r; lcur[i] = r; r += lcnt[i]; }
  }
  __syncthreads();
  for (unsigned i = t; i < m; i += 256) {
    const unsigned v = pk[base + i];
    const unsigned p = atomicAdd(&lcur[v >> 16], 1u);
    csr[base + p] = (unsigned short)(v & 0xFFFFu);
  }
  __syncthreads();
  if (t < RNODES) {
    const int v = b * RNODES + t;
    if (v < N) {
      offsets[v] = (int)(base + loffs[t]);
      counts[v]  = (int)lcnt[t];
    }
  }
}

// ---------------------------------------------------------------------------
// Sliced gather-reduce.  One wave per (node, slice); grid slice-major so all
// concurrent blocks hammer the same 3.2 MB L2-resident slice.  Quarter-wave
// (16 lanes, ushort2 = 64 B line) per edge; groups g=0..3 take edges
// k === g (mod 4); 2x unroll -> 8 gathers in flight per wave.  csr id read
// directly per group (16 lanes same address -> broadcast); NO shfl, NO
// nontemporal stores (R5 suspects removed).
// ---------------------------------------------------------------------------
__global__ __launch_bounds__(256) void k_reduce(
    const unsigned short* __restrict__ Ys,   // [4][N][32] bf16
    const int* __restrict__ offsets,
    const int* __restrict__ counts,
    const unsigned short* __restrict__ csr,
    const float* __restrict__ b,
    float* __restrict__ out,                  // [N][128] f32
    int N, int bps) {                         // bps = ceil(N/4)
  const int lane = threadIdx.x & 63;
  const int g    = lane >> 4;                 // edge group 0..3
  const int q    = lane & 15;                 // column pair within slice
  const int s    = blockIdx.x / bps;          // slice 0..3
  const int v    = (blockIdx.x % bps) * 4 + (threadIdx.x >> 6);
  if (v >= N) return;
  const int off = offsets[v];
  const int deg = counts[v];
  const unsigned short* Yslice = Ys + (size_t)s * N * 32;

  float ax = 0.f, ay = 0.f;
  int k = g;
  for (; k + 4 < deg; k += 8) {               // edges k and k+4 this iter
    const int s0 = (int)csr[off + k];
    const int s1 = (int)csr[off + k + 4];
    const ushort2 y0 = *reinterpret_cast<const ushort2*>(
        Yslice + (size_t)s0 * 32 + q * 2);
    const ushort2 y1 = *reinterpret_cast<const ushort2*>(
        Yslice + (size_t)s1 * 32 + q * 2);
    ax += bf2f(y0.x) + bf2f(y1.x);
    ay += bf2f(y0.y) + bf2f(y1.y);
  }
  for (; k < deg; k += 4) {
    const int s0 = (int)csr[off + k];
    const ushort2 y = *reinterpret_cast<const ushort2*>(
        Yslice + (size_t)s0 * 32 + q * 2);
    ax += bf2f(y.x); ay += bf2f(y.y);
  }

  ax += __shfl_xor(ax, 16); ax += __shfl_xor(ax, 32);
  ay += __shfl_xor(ay, 16); ay += __shfl_xor(ay, 32);
  if (g == 0) {
    const int j = s * 32 + q * 2;
    float2 o = make_float2(ax + b[j], ay + b[j + 1]);
    *reinterpret_cast<float2*>(out + (size_t)v * F + j) = o;
  }
}

// ---------------------------------------------------------------------------
// Overflow fallback (expected empty): wave per edge, fp32 atomics into out.
// ---------------------------------------------------------------------------
__global__ __launch_bounds__(256) void k_overflow(
    const unsigned* __restrict__ ovcnt,
    const unsigned long long* __restrict__ ovlist,
    const unsigned short* __restrict__ Ys,
    float* __restrict__ out, int N) {
  const unsigned n = min(*ovcnt, (unsigned)OVCAP);
  const int lane = threadIdx.x & 63;
  const int w  = (int)((blockIdx.x * blockDim.x + threadIdx.x) >> 6);
  const int nw = (int)((gridDim.x * blockDim.x) >> 6);
  const int j0 = lane * 2;
  const int sl = j0 >> 5, c = j0 & 31;
  for (unsigned i = w; i < n; i += nw) {
    const unsigned long long e = ovlist[i];
    const unsigned s = (unsigned)(e & 0xFFFFFFFFu);
    const unsigned d = (unsigned)(e >> 32);
    const unsigned short* row = Ys + ((size_t)sl * N + s) * 32;
    unsafeAtomicAdd(&out[(size_t)d * F + j0],     bf2f(row[c]));
    unsafeAtomicAdd(&out[(size_t)d * F + j0 + 1], bf2f(row[c + 1]));
  }
}

extern "C" void kernel_launch(void* const* d_in, const int* in_sizes, int n_in,
                              void* d_out, int out_size, void* d_ws, size_t ws_size,
                              hipStream_t stream) {
  const float* feat = (const float*)d_in[0];
  const int*   src  = (const int*)d_in[1];
  const int*   dst  = (const int*)d_in[2];
  const float* W    = (const float*)d_in[3];
  const float* b    = (const float*)d_in[4];
  float*       out  = (float*)d_out;

  const int N = in_sizes[0] / F;   // 50000
  const int E = in_sizes[1];       // 1600000

  char* w = (char*)d_ws;
  auto alloc = [&](size_t bytes) {
    char* p = w; w += (bytes + 255) & ~(size_t)255; return p;
  };
  unsigned short*     Ys      = (unsigned short*)alloc((size_t)N * F * 2);
  short*              Wp      = (short*)alloc(2048 * 8 * 2);
  unsigned*           pk      = (unsigned*)alloc((size_t)NBUCK * CB * 4);
  unsigned short*     csr     = (unsigned short*)alloc((size_t)NBUCK * CB * 2);
  int*                offsets = (int*)alloc((size_t)N * 4);
  int*                counts  = (int*)alloc((size_t)N * 4);
  unsigned*           gcur    = (unsigned*)alloc((size_t)NBUCK * 4);
  unsigned*           ovcnt   = (unsigned*)alloc(4);
  unsigned long long* ovlist  = (unsigned long long*)alloc((size_t)OVCAP * 8);

  k_init<<<(NBUCK + 256) / 256, 256, 0, stream>>>(gcur, ovcnt);
  k_packW<<<1, 256, 0, stream>>>(W, Wp);

  const int nTiles = (N + 15) / 16;                       // 3125
  k_gemm<<<(nTiles + 3) / 4, 256, 0, stream>>>(feat, Wp, Ys, N, nTiles);

  const int nchunk = (E + CH - 1) / CH;                   // 196
  k_partition<<<nchunk, 512, 0, stream>>>(src, dst, pk, gcur, ovcnt, ovlist, E);
  k_csr<<<NBUCK, 256, 0, stream>>>(pk, gcur, csr, offsets, counts, N);

  const int bps = (N + 3) / 4;                            // 12500
  k_reduce<<<4 * bps, 256, 0, stream>>>(
      Ys, offsets, counts, csr, b, out, N, bps);
  k_overflow<<<16, 256, 0, stream>>>(ovcnt, ovlist, Ys, out, N);
}

// Round 7
// 120.412 us; speedup vs baseline: 1.3154x; 1.3154x over previous
//
#include <hip/hip_runtime.h>

#define F      128
#define RSH    5            // 32 nodes per bucket
#define RNODES 32
#define NBUCK  1563         // ceil(50000/32) — N fixed at 50000
#define CB     1280         // bucket capacity (mean 1024, +8 sigma)
#define CH     8192         // edges per partition chunk
#define OVCAP  65536

typedef __attribute__((ext_vector_type(8))) short short8;   // 8 bf16
typedef __attribute__((ext_vector_type(4))) float f32x4;    // MFMA C/D frag

__device__ inline short f2bf(float f) {        // fp32 -> bf16 RNE
  unsigned u = __float_as_uint(f);
  u += 0x7fff + ((u >> 16) & 1);
  return (short)(u >> 16);
}
__device__ inline float bf2f(unsigned short u) {
  return __uint_as_float((unsigned)u << 16);
}

// ---------------------------------------------------------------------------
// Init: bucket cursors at region base; overflow count = 0.
// ---------------------------------------------------------------------------
__global__ __launch_bounds__(256) void k_init(unsigned* gcur, unsigned* ovcnt) {
  const int i = blockIdx.x * blockDim.x + threadIdx.x;
  if (i < NBUCK) gcur[i] = (unsigned)i * CB;
  else if (i == NBUCK) *ovcnt = 0;
}

// ---------------------------------------------------------------------------
// Pack W into MFMA B-fragments (bf16), one-time 32KB buffer (L1/L2-resident).
// ---------------------------------------------------------------------------
__global__ __launch_bounds__(256) void k_packW(
    const float* __restrict__ W, short* __restrict__ Wp) {
  for (int fid = threadIdx.x; fid < 2048; fid += 256) {
    const int lane = fid & 63;
    const int c    = (fid >> 6) & 3;
    const int jt   = fid >> 8;
    const int j    = jt * 16 + (lane & 15);
    const int k0   = c * 32 + (lane >> 4) * 8;
    short8 s;
    #pragma unroll
    for (int i = 0; i < 8; ++i) s[i] = f2bf(W[j * F + k0 + i]);
    *reinterpret_cast<short8*>(Wp + fid * 8) = s;
  }
}

// ---------------------------------------------------------------------------
// Y = X @ W^T via mfma_f32_16x16x32_bf16; output bf16 in COLUMN-SLICED layout
// Ys[s][row][c]  (s = col>>5, c = col&31): each 32-col slice is 3.2 MB ->
// per-XCD-L2-resident during the sliced reduce.  (verbatim from R6 — proven)
// ---------------------------------------------------------------------------
__global__ __launch_bounds__(256) void k_gemm(
    const float* __restrict__ X, const short* __restrict__ Wp,
    unsigned short* __restrict__ Ys, int N, int nTiles) {
  const int lane = threadIdx.x & 63;
  const int tile = blockIdx.x * 4 + (threadIdx.x >> 6);
  if (tile >= nTiles) return;
  const int row0 = tile * 16;
  const int r    = row0 + (lane & 15);
  const int k0   = (lane >> 4) * 8;
  const size_t NS = (size_t)N * 32;

  short8 a[4];
  #pragma unroll
  for (int c = 0; c < 4; ++c) {
    if (r < N) {
      const float* p = X + (size_t)r * F + c * 32 + k0;
      const float4 x0 = *reinterpret_cast<const float4*>(p);
      const float4 x1 = *reinterpret_cast<const float4*>(p + 4);
      a[c][0] = f2bf(x0.x); a[c][1] = f2bf(x0.y);
      a[c][2] = f2bf(x0.z); a[c][3] = f2bf(x0.w);
      a[c][4] = f2bf(x1.x); a[c][5] = f2bf(x1.y);
      a[c][6] = f2bf(x1.z); a[c][7] = f2bf(x1.w);
    } else {
      #pragma unroll
      for (int i = 0; i < 8; ++i) a[c][i] = 0;
    }
  }

  #pragma unroll
  for (int jt = 0; jt < 8; ++jt) {
    f32x4 acc = {0.f, 0.f, 0.f, 0.f};
    #pragma unroll
    for (int c = 0; c < 4; ++c) {
      const short8 bfrag = *reinterpret_cast<const short8*>(
          Wp + ((jt * 4 + c) * 64 + lane) * 8);
      acc = __builtin_amdgcn_mfma_f32_16x16x32_bf16(a[c], bfrag, acc, 0, 0, 0);
    }
    const int col   = jt * 16 + (lane & 15);
    const int rbase = row0 + (lane >> 4) * 4;
    unsigned short* dst = Ys + (size_t)(col >> 5) * NS + (col & 31);
    #pragma unroll
    for (int reg = 0; reg < 4; ++reg)
      if (rbase + reg < N)
        dst[(size_t)(rbase + reg) * 32] = (unsigned short)f2bf(acc[reg]);
  }
}

// ---------------------------------------------------------------------------
// Multisplit partition (verbatim — proven).
// Entry = src(16b) | dst_local(5b)<<16 | bucket(11b)<<21.
// ---------------------------------------------------------------------------
__global__ __launch_bounds__(512) void k_partition(
    const int* __restrict__ src, const int* __restrict__ dst,
    unsigned* __restrict__ pk, unsigned* __restrict__ gcur,
    unsigned* __restrict__ ovcnt, unsigned long long* __restrict__ ovlist,
    int E) {
  __shared__ unsigned lpk[CH];
  __shared__ unsigned cnt[NBUCK];
  __shared__ unsigned offs[NBUCK];
  __shared__ unsigned cur[NBUCK];
  __shared__ unsigned gbase[NBUCK];
  const int t = threadIdx.x;
  const int nchunk = (E + CH - 1) / CH;

  for (int c = blockIdx.x; c < nchunk; c += gridDim.x) {
    const int e0   = c * CH;
    const int ecnt = min(CH, E - e0);

    for (int i = t; i < NBUCK; i += 512) cnt[i] = 0;
    __syncthreads();

    for (int i = t; i < ecnt; i += 512)
      atomicAdd(&cnt[(unsigned)dst[e0 + i] >> RSH], 1u);
    __syncthreads();

    unsigned lv0, lv1, lv2, lv3;
    {
      const int i0 = t * 4;
      lv0 = (i0 + 0 < NBUCK) ? cnt[i0 + 0] : 0;
      lv1 = (i0 + 1 < NBUCK) ? cnt[i0 + 1] : 0;
      lv2 = (i0 + 2 < NBUCK) ? cnt[i0 + 2] : 0;
      lv3 = (i0 + 3 < NBUCK) ? cnt[i0 + 3] : 0;
    }
    cur[t] = lv0 + lv1 + lv2 + lv3;
    __syncthreads();
    for (int d2 = 1; d2 < 512; d2 <<= 1) {
      const unsigned add = (t >= d2) ? cur[t - d2] : 0;
      __syncthreads();
      cur[t] += add;
      __syncthreads();
    }
    unsigned ebase = (t > 0) ? cur[t - 1] : 0;
    __syncthreads();
    {
      const int i0 = t * 4;
      if (i0 + 0 < NBUCK) { offs[i0 + 0] = ebase; cur[i0 + 0] = ebase; ebase += lv0; }
      if (i0 + 1 < NBUCK) { offs[i0 + 1] = ebase; cur[i0 + 1] = ebase; ebase += lv1; }
      if (i0 + 2 < NBUCK) { offs[i0 + 2] = ebase; cur[i0 + 2] = ebase; ebase += lv2; }
      if (i0 + 3 < NBUCK) { offs[i0 + 3] = ebase; cur[i0 + 3] = ebase; ebase += lv3; }
    }
    __syncthreads();

    for (int i = t; i < ecnt; i += 512) {
      const unsigned d = (unsigned)dst[e0 + i];
      const unsigned b = d >> RSH;
      const unsigned p = atomicAdd(&cur[b], 1u);
      lpk[p] = (unsigned)src[e0 + i] | ((d & (RNODES - 1)) << 16) | (b << 21);
    }
    __syncthreads();

    for (int i = t; i < NBUCK; i += 512)
      if (cnt[i] > 0) gbase[i] = atomicAdd(&gcur[i], cnt[i]);
    __syncthreads();

    for (int p = t; p < ecnt; p += 512) {
      const unsigned v = lpk[p];
      const unsigned b = v >> 21;
      const unsigned idx = gbase[b] + ((unsigned)p - offs[b]);
      if (idx < (b + 1) * (unsigned)CB) {
        pk[idx] = v & 0x1FFFFFu;
      } else {
        const unsigned o = atomicAdd(ovcnt, 1u);
        if (o < OVCAP) {
          const unsigned s  = v & 0xFFFFu;
          const unsigned dl = (v >> 16) & (RNODES - 1);
          ovlist[o] = ((unsigned long long)(b * RNODES + dl) << 32) | s;
        }
      }
    }
    __syncthreads();
  }
}

// ---------------------------------------------------------------------------
// Per-bucket CSR (verbatim — proven).
// ---------------------------------------------------------------------------
__global__ __launch_bounds__(256) void k_csr(
    const unsigned* __restrict__ pk, const unsigned* __restrict__ gcur,
    unsigned short* __restrict__ csr, int* __restrict__ offsets,
    int* __restrict__ counts, int N) {
  __shared__ unsigned lcnt[RNODES], loffs[RNODES], lcur[RNODES];
  const int b = blockIdx.x;
  const unsigned base = (unsigned)b * CB;
  const unsigned m = min(gcur[b] - base, (unsigned)CB);
  const int t = threadIdx.x;
  if (t < RNODES) lcnt[t] = 0;
  __syncthreads();
  for (unsigned i = t; i < m; i += 256)
    atomicAdd(&lcnt[pk[base + i] >> 16], 1u);
  __syncthreads();
  if (t == 0) {
    unsigned r = 0;
    #pragma unroll
    for (int i = 0; i < RNODES; ++i) { loffs[i] = r; lcur[i] = r; r += lcnt[i]; }
  }
  __syncthreads();
  for (unsigned i = t; i < m; i += 256) {
    const unsigned v = pk[base + i];
    const unsigned p = atomicAdd(&lcur[v >> 16], 1u);
    csr[base + p] = (unsigned short)(v & 0xFFFFu);
  }
  __syncthreads();
  if (t < RNODES) {
    const int v = b * RNODES + t;
    if (v < N) {
      offsets[v] = (int)(base + loffs[t]);
      counts[v]  = (int)lcnt[t];
    }
  }
}

// ---------------------------------------------------------------------------
// Sliced gather-reduce, quarter-wave-per-node decomposition.
// Wave = 4 nodes x 1 slice; lane (g,q): node v_g, column pair q.  Each lane
// accumulates its own 2 output columns over ALL its node's edges -> no
// cross-lane reduction at all.  csr walked once per (node,slice); 4x unroll
// = 16 concurrent 64B gathers per wave.  Grid slice-major: all concurrent
// blocks hammer the same 3.2 MB L2-resident slice.
// ---------------------------------------------------------------------------
__global__ __launch_bounds__(256) void k_reduce(
    const unsigned short* __restrict__ Ys,   // [4][N][32] bf16
    const int* __restrict__ offsets,
    const int* __restrict__ counts,
    const unsigned short* __restrict__ csr,
    const float* __restrict__ b,
    float* __restrict__ out,                  // [N][128] f32
    int N, int bpn) {                         // bpn = ceil(N/16)
  const int lane = threadIdx.x & 63;
  const int g    = lane >> 4;                 // node group 0..3
  const int q    = lane & 15;                 // column pair within slice
  const int s    = blockIdx.x / bpn;          // slice 0..3
  const int v    = (blockIdx.x % bpn) * 16 + (threadIdx.x >> 6) * 4 + g;
  const bool valid = (v < N);
  const int off = valid ? offsets[v] : 0;
  const int deg = valid ? counts[v] : 0;
  const unsigned short* Yslice = Ys + (size_t)s * N * 32;

  float ax = 0.f, ay = 0.f;
  int k = 0;
  for (; k + 3 < deg; k += 4) {               // 4 gathers in flight per group
    const int s0 = (int)csr[off + k];
    const int s1 = (int)csr[off + k + 1];
    const int s2 = (int)csr[off + k + 2];
    const int s3 = (int)csr[off + k + 3];
    const ushort2 y0 = *reinterpret_cast<const ushort2*>(
        Yslice + (size_t)s0 * 32 + q * 2);
    const ushort2 y1 = *reinterpret_cast<const ushort2*>(
        Yslice + (size_t)s1 * 32 + q * 2);
    const ushort2 y2 = *reinterpret_cast<const ushort2*>(
        Yslice + (size_t)s2 * 32 + q * 2);
    const ushort2 y3 = *reinterpret_cast<const ushort2*>(
        Yslice + (size_t)s3 * 32 + q * 2);
    ax += bf2f(y0.x) + bf2f(y1.x) + bf2f(y2.x) + bf2f(y3.x);
    ay += bf2f(y0.y) + bf2f(y1.y) + bf2f(y2.y) + bf2f(y3.y);
  }
  for (; k < deg; ++k) {
    const int s0 = (int)csr[off + k];
    const ushort2 y = *reinterpret_cast<const ushort2*>(
        Yslice + (size_t)s0 * 32 + q * 2);
    ax += bf2f(y.x); ay += bf2f(y.y);
  }

  if (valid) {
    const int j = s * 32 + q * 2;
    float2 o = make_float2(ax + b[j], ay + b[j + 1]);
    *reinterpret_cast<float2*>(out + (size_t)v * F + j) = o;
  }
}

// ---------------------------------------------------------------------------
// Overflow fallback (expected empty): wave per edge, fp32 atomics into out.
// ---------------------------------------------------------------------------
__global__ __launch_bounds__(256) void k_overflow(
    const unsigned* __restrict__ ovcnt,
    const unsigned long long* __restrict__ ovlist,
    const unsigned short* __restrict__ Ys,
    float* __restrict__ out, int N) {
  const unsigned n = min(*ovcnt, (unsigned)OVCAP);
  const int lane = threadIdx.x & 63;
  const int w  = (int)((blockIdx.x * blockDim.x + threadIdx.x) >> 6);
  const int nw = (int)((gridDim.x * blockDim.x) >> 6);
  const int j0 = lane * 2;
  const int sl = j0 >> 5, c = j0 & 31;
  for (unsigned i = w; i < n; i += nw) {
    const unsigned long long e = ovlist[i];
    const unsigned s = (unsigned)(e & 0xFFFFFFFFu);
    const unsigned d = (unsigned)(e >> 32);
    const unsigned short* row = Ys + ((size_t)sl * N + s) * 32;
    unsafeAtomicAdd(&out[(size_t)d * F + j0],     bf2f(row[c]));
    unsafeAtomicAdd(&out[(size_t)d * F + j0 + 1], bf2f(row[c + 1]));
  }
}

extern "C" void kernel_launch(void* const* d_in, const int* in_sizes, int n_in,
                              void* d_out, int out_size, void* d_ws, size_t ws_size,
                              hipStream_t stream) {
  const float* feat = (const float*)d_in[0];
  const int*   src  = (const int*)d_in[1];
  const int*   dst  = (const int*)d_in[2];
  const float* W    = (const float*)d_in[3];
  const float* b    = (const float*)d_in[4];
  float*       out  = (float*)d_out;

  const int N = in_sizes[0] / F;   // 50000
  const int E = in_sizes[1];       // 1600000

  char* w = (char*)d_ws;
  auto alloc = [&](size_t bytes) {
    char* p = w; w += (bytes + 255) & ~(size_t)255; return p;
  };
  unsigned short*     Ys      = (unsigned short*)alloc((size_t)N * F * 2);
  short*              Wp      = (short*)alloc(2048 * 8 * 2);
  unsigned*           pk      = (unsigned*)alloc((size_t)NBUCK * CB * 4);
  unsigned short*     csr     = (unsigned short*)alloc((size_t)NBUCK * CB * 2);
  int*                offsets = (int*)alloc((size_t)N * 4);
  int*                counts  = (int*)alloc((size_t)N * 4);
  unsigned*           gcur    = (unsigned*)alloc((size_t)NBUCK * 4);
  unsigned*           ovcnt   = (unsigned*)alloc(4);
  unsigned long long* ovlist  = (unsigned long long*)alloc((size_t)OVCAP * 8);

  k_init<<<(NBUCK + 256) / 256, 256, 0, stream>>>(gcur, ovcnt);
  k_packW<<<1, 256, 0, stream>>>(W, Wp);

  const int nTiles = (N + 15) / 16;                       // 3125
  k_gemm<<<(nTiles + 3) / 4, 256, 0, stream>>>(feat, Wp, Ys, N, nTiles);

  const int nchunk = (E + CH - 1) / CH;                   // 196
  k_partition<<<nchunk, 512, 0, stream>>>(src, dst, pk, gcur, ovcnt, ovlist, E);
  k_csr<<<NBUCK, 256, 0, stream>>>(pk, gcur, csr, offsets, counts, N);

  const int bpn = (N + 15) / 16;                          // 3125
  k_reduce<<<4 * bpn, 256, 0, stream>>>(
      Ys, offsets, counts, csr, b, out, N, bpn);
  k_overflow<<<16, 256, 0, stream>>>(ovcnt, ovlist, Ys, out, N);
}

// Round 8
// 106.509 us; speedup vs baseline: 1.4871x; 1.1305x over previous
//
#include <hip/hip_runtime.h>

#define F      128
#define RSH    5            // 32 nodes per bucket
#define RNODES 32
#define NBUCK  1563         // ceil(50000/32) — N fixed at 50000
#define CB     1280         // bucket capacity (mean 1024, +8 sigma)
#define CH     8192         // edges per partition chunk
#define OVCAP  65536

typedef __attribute__((ext_vector_type(8))) short short8;            // 8 bf16
typedef __attribute__((ext_vector_type(8))) unsigned short ushort8v; // 8 bf16
typedef __attribute__((ext_vector_type(4))) float f32x4;             // MFMA C/D

__device__ inline short f2bf(float f) {        // fp32 -> bf16 RNE
  unsigned u = __float_as_uint(f);
  u += 0x7fff + ((u >> 16) & 1);
  return (short)(u >> 16);
}
__device__ inline float bf2f(unsigned short u) {
  return __uint_as_float((unsigned)u << 16);
}

// ---------------------------------------------------------------------------
// Init: bucket cursors at region base; overflow count = 0.
// ---------------------------------------------------------------------------
__global__ __launch_bounds__(256) void k_init(unsigned* gcur, unsigned* ovcnt) {
  const int i = blockIdx.x * blockDim.x + threadIdx.x;
  if (i < NBUCK) gcur[i] = (unsigned)i * CB;
  else if (i == NBUCK) *ovcnt = 0;
}

// ---------------------------------------------------------------------------
// Pack W into MFMA B-fragments (bf16), one-time 32KB buffer (L1/L2-resident).
// ---------------------------------------------------------------------------
__global__ __launch_bounds__(256) void k_packW(
    const float* __restrict__ W, short* __restrict__ Wp) {
  for (int fid = threadIdx.x; fid < 2048; fid += 256) {
    const int lane = fid & 63;
    const int c    = (fid >> 6) & 3;
    const int jt   = fid >> 8;
    const int j    = jt * 16 + (lane & 15);
    const int k0   = c * 32 + (lane >> 4) * 8;
    short8 s;
    #pragma unroll
    for (int i = 0; i < 8; ++i) s[i] = f2bf(W[j * F + k0 + i]);
    *reinterpret_cast<short8*>(Wp + fid * 8) = s;
  }
}

// ---------------------------------------------------------------------------
// Y = X @ W^T via mfma_f32_16x16x32_bf16; output bf16 ROW-MAJOR [N][128]
// (R4-proven store: col=jt*16+(lane&15); row=row0+(lane>>4)*4+reg).
// ---------------------------------------------------------------------------
__global__ __launch_bounds__(256) void k_gemm(
    const float* __restrict__ X, const short* __restrict__ Wp,
    unsigned short* __restrict__ Yb, int N, int nTiles) {
  const int lane = threadIdx.x & 63;
  const int tile = blockIdx.x * 4 + (threadIdx.x >> 6);
  if (tile >= nTiles) return;
  const int row0 = tile * 16;
  const int r    = row0 + (lane & 15);
  const int k0   = (lane >> 4) * 8;

  short8 a[4];
  #pragma unroll
  for (int c = 0; c < 4; ++c) {
    if (r < N) {
      const float* p = X + (size_t)r * F + c * 32 + k0;
      const float4 x0 = *reinterpret_cast<const float4*>(p);
      const float4 x1 = *reinterpret_cast<const float4*>(p + 4);
      a[c][0] = f2bf(x0.x); a[c][1] = f2bf(x0.y);
      a[c][2] = f2bf(x0.z); a[c][3] = f2bf(x0.w);
      a[c][4] = f2bf(x1.x); a[c][5] = f2bf(x1.y);
      a[c][6] = f2bf(x1.z); a[c][7] = f2bf(x1.w);
    } else {
      #pragma unroll
      for (int i = 0; i < 8; ++i) a[c][i] = 0;
    }
  }

  #pragma unroll
  for (int jt = 0; jt < 8; ++jt) {
    f32x4 acc = {0.f, 0.f, 0.f, 0.f};
    #pragma unroll
    for (int c = 0; c < 4; ++c) {
      const short8 bfrag = *reinterpret_cast<const short8*>(
          Wp + ((jt * 4 + c) * 64 + lane) * 8);
      acc = __builtin_amdgcn_mfma_f32_16x16x32_bf16(a[c], bfrag, acc, 0, 0, 0);
    }
    const int col   = jt * 16 + (lane & 15);
    const int rbase = row0 + (lane >> 4) * 4;
    #pragma unroll
    for (int reg = 0; reg < 4; ++reg)
      if (rbase + reg < N)
        Yb[(size_t)(rbase + reg) * F + col] = (unsigned short)f2bf(acc[reg]);
  }
}

// ---------------------------------------------------------------------------
// Multisplit partition (verbatim — proven).
// Entry = src(16b) | dst_local(5b)<<16 | bucket(11b)<<21.
// ---------------------------------------------------------------------------
__global__ __launch_bounds__(512) void k_partition(
    const int* __restrict__ src, const int* __restrict__ dst,
    unsigned* __restrict__ pk, unsigned* __restrict__ gcur,
    unsigned* __restrict__ ovcnt, unsigned long long* __restrict__ ovlist,
    int E) {
  __shared__ unsigned lpk[CH];
  __shared__ unsigned cnt[NBUCK];
  __shared__ unsigned offs[NBUCK];
  __shared__ unsigned cur[NBUCK];
  __shared__ unsigned gbase[NBUCK];
  const int t = threadIdx.x;
  const int nchunk = (E + CH - 1) / CH;

  for (int c = blockIdx.x; c < nchunk; c += gridDim.x) {
    const int e0   = c * CH;
    const int ecnt = min(CH, E - e0);

    for (int i = t; i < NBUCK; i += 512) cnt[i] = 0;
    __syncthreads();

    for (int i = t; i < ecnt; i += 512)
      atomicAdd(&cnt[(unsigned)dst[e0 + i] >> RSH], 1u);
    __syncthreads();

    unsigned lv0, lv1, lv2, lv3;
    {
      const int i0 = t * 4;
      lv0 = (i0 + 0 < NBUCK) ? cnt[i0 + 0] : 0;
      lv1 = (i0 + 1 < NBUCK) ? cnt[i0 + 1] : 0;
      lv2 = (i0 + 2 < NBUCK) ? cnt[i0 + 2] : 0;
      lv3 = (i0 + 3 < NBUCK) ? cnt[i0 + 3] : 0;
    }
    cur[t] = lv0 + lv1 + lv2 + lv3;
    __syncthreads();
    for (int d2 = 1; d2 < 512; d2 <<= 1) {
      const unsigned add = (t >= d2) ? cur[t - d2] : 0;
      __syncthreads();
      cur[t] += add;
      __syncthreads();
    }
    unsigned ebase = (t > 0) ? cur[t - 1] : 0;
    __syncthreads();
    {
      const int i0 = t * 4;
      if (i0 + 0 < NBUCK) { offs[i0 + 0] = ebase; cur[i0 + 0] = ebase; ebase += lv0; }
      if (i0 + 1 < NBUCK) { offs[i0 + 1] = ebase; cur[i0 + 1] = ebase; ebase += lv1; }
      if (i0 + 2 < NBUCK) { offs[i0 + 2] = ebase; cur[i0 + 2] = ebase; ebase += lv2; }
      if (i0 + 3 < NBUCK) { offs[i0 + 3] = ebase; cur[i0 + 3] = ebase; ebase += lv3; }
    }
    __syncthreads();

    for (int i = t; i < ecnt; i += 512) {
      const unsigned d = (unsigned)dst[e0 + i];
      const unsigned b = d >> RSH;
      const unsigned p = atomicAdd(&cur[b], 1u);
      lpk[p] = (unsigned)src[e0 + i] | ((d & (RNODES - 1)) << 16) | (b << 21);
    }
    __syncthreads();

    for (int i = t; i < NBUCK; i += 512)
      if (cnt[i] > 0) gbase[i] = atomicAdd(&gcur[i], cnt[i]);
    __syncthreads();

    for (int p = t; p < ecnt; p += 512) {
      const unsigned v = lpk[p];
      const unsigned b = v >> 21;
      const unsigned idx = gbase[b] + ((unsigned)p - offs[b]);
      if (idx < (b + 1) * (unsigned)CB) {
        pk[idx] = v & 0x1FFFFFu;
      } else {
        const unsigned o = atomicAdd(ovcnt, 1u);
        if (o < OVCAP) {
          const unsigned s  = v & 0xFFFFu;
          const unsigned dl = (v >> 16) & (RNODES - 1);
          ovlist[o] = ((unsigned long long)(b * RNODES + dl) << 32) | s;
        }
      }
    }
    __syncthreads();
  }
}

// ---------------------------------------------------------------------------
// Per-bucket CSR (verbatim — proven).
// ---------------------------------------------------------------------------
__global__ __launch_bounds__(256) void k_csr(
    const unsigned* __restrict__ pk, const unsigned* __restrict__ gcur,
    unsigned short* __restrict__ csr, int* __restrict__ offsets,
    int* __restrict__ counts, int N) {
  __shared__ unsigned lcnt[RNODES], loffs[RNODES], lcur[RNODES];
  const int b = blockIdx.x;
  const unsigned base = (unsigned)b * CB;
  const unsigned m = min(gcur[b] - base, (unsigned)CB);
  const int t = threadIdx.x;
  if (t < RNODES) lcnt[t] = 0;
  __syncthreads();
  for (unsigned i = t; i < m; i += 256)
    atomicAdd(&lcnt[pk[base + i] >> 16], 1u);
  __syncthreads();
  if (t == 0) {
    unsigned r = 0;
    #pragma unroll
    for (int i = 0; i < RNODES; ++i) { loffs[i] = r; lcur[i] = r; r += lcnt[i]; }
  }
  __syncthreads();
  for (unsigned i = t; i < m; i += 256) {
    const unsigned v = pk[base + i];
    const unsigned p = atomicAdd(&lcur[v >> 16], 1u);
    csr[base + p] = (unsigned short)(v & 0xFFFFu);
  }
  __syncthreads();
  if (t < RNODES) {
    const int v = b * RNODES + t;
    if (v < N) {
      offsets[v] = (int)(base + loffs[t]);
      counts[v]  = (int)lcnt[t];
    }
  }
}

// ---------------------------------------------------------------------------
// Full-row gather-reduce, quarter-wave per node, SINGLE pass.
// Lane (g,q): node v_g, columns [q*8, q*8+8).  Per edge, the 16-lane group
// reads the whole 256B bf16 row as ushort8/lane = 2x128B L2 requests
// (half of R7's 4x64B).  4-deep unroll = 4 gathers (8 requests) in flight
// per group, 16 gathers per wave.  No cross-lane reduction; csr walked once.
// ---------------------------------------------------------------------------
__global__ __launch_bounds__(256) void k_reduce(
    const unsigned short* __restrict__ Yb,   // [N][128] bf16 row-major
    const int* __restrict__ offsets,
    const int* __restrict__ counts,
    const unsigned short* __restrict__ csr,
    const float* __restrict__ b,
    float* __restrict__ out,                  // [N][128] f32
    int N) {
  const int lane = threadIdx.x & 63;
  const int g    = lane >> 4;                 // node group 0..3
  const int q    = lane & 15;                 // 8-col chunk within row
  const int v    = blockIdx.x * 16 + (threadIdx.x >> 6) * 4 + g;
  const bool valid = (v < N);
  const int off = valid ? offsets[v] : 0;
  const int deg = valid ? counts[v] : 0;

  float acc[8];
  #pragma unroll
  for (int j = 0; j < 8; ++j) acc[j] = 0.f;

  int k = 0;
  for (; k + 3 < deg; k += 4) {               // 4 gathers in flight per group
    const int s0 = (int)csr[off + k];
    const int s1 = (int)csr[off + k + 1];
    const int s2 = (int)csr[off + k + 2];
    const int s3 = (int)csr[off + k + 3];
    const ushort8v y0 = *reinterpret_cast<const ushort8v*>(
        Yb + (size_t)s0 * F + q * 8);
    const ushort8v y1 = *reinterpret_cast<const ushort8v*>(
        Yb + (size_t)s1 * F + q * 8);
    const ushort8v y2 = *reinterpret_cast<const ushort8v*>(
        Yb + (size_t)s2 * F + q * 8);
    const ushort8v y3 = *reinterpret_cast<const ushort8v*>(
        Yb + (size_t)s3 * F + q * 8);
    #pragma unroll
    for (int j = 0; j < 8; ++j)
      acc[j] += (bf2f(y0[j]) + bf2f(y1[j])) + (bf2f(y2[j]) + bf2f(y3[j]));
  }
  for (; k < deg; ++k) {
    const int s0 = (int)csr[off + k];
    const ushort8v y = *reinterpret_cast<const ushort8v*>(
        Yb + (size_t)s0 * F + q * 8);
    #pragma unroll
    for (int j = 0; j < 8; ++j) acc[j] += bf2f(y[j]);
  }

  if (valid) {
    float* op = out + (size_t)v * F + q * 8;
    const float4 b0 = *reinterpret_cast<const float4*>(b + q * 8);
    const float4 b1 = *reinterpret_cast<const float4*>(b + q * 8 + 4);
    float4 o0 = make_float4(acc[0] + b0.x, acc[1] + b0.y,
                            acc[2] + b0.z, acc[3] + b0.w);
    float4 o1 = make_float4(acc[4] + b1.x, acc[5] + b1.y,
                            acc[6] + b1.z, acc[7] + b1.w);
    *reinterpret_cast<float4*>(op)     = o0;
    *reinterpret_cast<float4*>(op + 4) = o1;
  }
}

// ---------------------------------------------------------------------------
// Overflow fallback (expected empty): wave per edge, fp32 atomics into out.
// ---------------------------------------------------------------------------
__global__ __launch_bounds__(256) void k_overflow(
    const unsigned* __restrict__ ovcnt,
    const unsigned long long* __restrict__ ovlist,
    const unsigned short* __restrict__ Yb,
    float* __restrict__ out, int N) {
  const unsigned n = min(*ovcnt, (unsigned)OVCAP);
  const int lane = threadIdx.x & 63;
  const int w  = (int)((blockIdx.x * blockDim.x + threadIdx.x) >> 6);
  const int nw = (int)((gridDim.x * blockDim.x) >> 6);
  for (unsigned i = w; i < n; i += nw) {
    const unsigned long long e = ovlist[i];
    const unsigned s = (unsigned)(e & 0xFFFFFFFFu);
    const unsigned d = (unsigned)(e >> 32);
    const float x0 = bf2f(Yb[(size_t)s * F + lane * 2]);
    const float x1 = bf2f(Yb[(size_t)s * F + lane * 2 + 1]);
    unsafeAtomicAdd(&out[(size_t)d * F + lane * 2],     x0);
    unsafeAtomicAdd(&out[(size_t)d * F + lane * 2 + 1], x1);
  }
}

extern "C" void kernel_launch(void* const* d_in, const int* in_sizes, int n_in,
                              void* d_out, int out_size, void* d_ws, size_t ws_size,
                              hipStream_t stream) {
  const float* feat = (const float*)d_in[0];
  const int*   src  = (const int*)d_in[1];
  const int*   dst  = (const int*)d_in[2];
  const float* W    = (const float*)d_in[3];
  const float* b    = (const float*)d_in[4];
  float*       out  = (float*)d_out;

  const int N = in_sizes[0] / F;   // 50000
  const int E = in_sizes[1];       // 1600000

  char* w = (char*)d_ws;
  auto alloc = [&](size_t bytes) {
    char* p = w; w += (bytes + 255) & ~(size_t)255; return p;
  };
  unsigned short*     Yb      = (unsigned short*)alloc((size_t)N * F * 2);
  short*              Wp      = (short*)alloc(2048 * 8 * 2);
  unsigned*           pk      = (unsigned*)alloc((size_t)NBUCK * CB * 4);
  unsigned short*     csr     = (unsigned short*)alloc((size_t)NBUCK * CB * 2);
  int*                offsets = (int*)alloc((size_t)N * 4);
  int*                counts  = (int*)alloc((size_t)N * 4);
  unsigned*           gcur    = (unsigned*)alloc((size_t)NBUCK * 4);
  unsigned*           ovcnt   = (unsigned*)alloc(4);
  unsigned long long* ovlist  = (unsigned long long*)alloc((size_t)OVCAP * 8);

  k_init<<<(NBUCK + 256) / 256, 256, 0, stream>>>(gcur, ovcnt);
  k_packW<<<1, 256, 0, stream>>>(W, Wp);

  const int nTiles = (N + 15) / 16;                       // 3125
  k_gemm<<<(nTiles + 3) / 4, 256, 0, stream>>>(feat, Wp, Yb, N, nTiles);

  const int nchunk = (E + CH - 1) / CH;                   // 196
  k_partition<<<nchunk, 512, 0, stream>>>(src, dst, pk, gcur, ovcnt, ovlist, E);
  k_csr<<<NBUCK, 256, 0, stream>>>(pk, gcur, csr, offsets, counts, N);

  k_reduce<<<(N + 15) / 16, 256, 0, stream>>>(
      Yb, offsets, counts, csr, b, out, N);
  k_overflow<<<16, 256, 0, stream>>>(ovcnt, ovlist, Yb, out, N);
}